// Round 6
// baseline (1215.665 us; speedup 1.0000x reference)
//
#include <hip/hip_runtime.h>

#define BATCH 512
#define TT 256
#define HH 256
#define HOR 22

__device__ __forceinline__ float rcp_(float x) { return __builtin_amdgcn_rcpf(x); }
__device__ __forceinline__ float sigmoidf_(float x) { return rcp_(1.0f + __expf(-x)); }
__device__ __forceinline__ float tanhf_(float x) {
    float e = __expf(-2.0f * fabsf(x));
    float t = (1.0f - e) * rcp_(1.0f + e);
    return copysignf(t, x);
}
__device__ __forceinline__ unsigned f2bf_rne(float f) {
    unsigned u = __float_as_uint(f);
    unsigned lsb = (u >> 16) & 1u;
    return (u + 0x7FFFu + lsb) >> 16;
}

// v_dot2_f32_bf16: acc += a.lo*b.lo + a.hi*b.hi (packed bf16 pairs)
#define DOT2(acc, a, b) asm("v_dot2_f32_bf16 %0, %1, %2, %0" : "+v"(acc) : "v"(a), "v"(b))
#define DOT2Q(accv, wq, hq)               \
    {                                     \
        DOT2(accv, (wq).x, (hq).x);       \
        DOT2(accv, (wq).y, (hq).y);       \
        DOT2(accv, (wq).z, (hq).z);       \
        DOT2(accv, (wq).w, (hq).w);       \
    }

// compiler barrier: pins a value into a register (kills remat/sinking of its load)
#define PIN(v) asm volatile("" : "+v"(v))
#define PIN4(q) { PIN((q).x); PIN((q).y); PIN((q).z); PIN((q).w); }

// DPP cross-lane (VALU pipe, no LDS)
#define DPPF(x, ctrl) __int_as_float(__builtin_amdgcn_update_dpp(0, __float_as_int(x), (ctrl), 0xF, 0xF, true))
#define RCOMB(out, a, b, p, ctrl)                          \
    {                                                      \
        float _ta = (a) + DPPF((a), ctrl);                 \
        float _tb = (b) + DPPF((b), ctrl);                 \
        (out) = (p) ? _tb : _ta;                           \
    }
// sum with lane^4 partner (within 16-lane row): verified mapping from rounds 2-5
#define SUM4(out, a, p2v)                                              \
    {                                                                  \
        float _x = (p2v) ? DPPF((a), 0x114) : DPPF((a), 0x104);        \
        (out) = (a) + _x;                                              \
    }

// ---------------- prep: transpose U matrices to packed-bf16 rows UT[col][kpair] ----------------
__global__ __launch_bounds__(256) void prep_kernel(const float* __restrict__ Uz,
                                                   const float* __restrict__ Ur,
                                                   const float* __restrict__ Uh,
                                                   unsigned* __restrict__ UzT,
                                                   unsigned* __restrict__ UrT,
                                                   unsigned* __restrict__ UhT) {
    int tid = blockIdx.x * 256 + threadIdx.x;   // 0 .. 98303
    int m  = tid >> 15;
    int r  = tid & 32767;
    int j  = r & 255;
    int kp = r >> 8;
    const float* src = (m == 0) ? Uz : (m == 1) ? Ur : Uh;
    unsigned*    dst = (m == 0) ? UzT : (m == 1) ? UrT : UhT;
    float a0 = src[(2 * kp)     * HH + j];
    float a1 = src[(2 * kp + 1) * HH + j];
    dst[j * (HH / 2) + kp] = f2bf_rne(a0) | (f2bf_rne(a1) << 16);
}

// ---------------- persistent GRU ----------------
// 256 WGs x 1024 thr; WG = 2 batch rows. thread t: K-slice s = t&7 (32 elems),
// col-pair cp = t>>3 (cols 2cp, 2cp+1). Uz+Ur resident in regs (64 dwords/thread,
// fits the hard 128-VGPR cap); Uh streamed from L2 each step (128KB/CU/step,
// hidden under VALU by 4 waves/SIMD).
__global__ __launch_bounds__(1024) void gru_kernel(
    const float* __restrict__ x,
    const float* __restrict__ Wzw, const float* __restrict__ Wzb, const float* __restrict__ Uzb,
    const float* __restrict__ Wrw, const float* __restrict__ Wrb, const float* __restrict__ Urb,
    const float* __restrict__ Whw, const float* __restrict__ Whb, const float* __restrict__ Uhb,
    const float* __restrict__ Wgw, const float* __restrict__ Wgb,
    const float* __restrict__ om_raw, const float* __restrict__ al_raw,
    const float* __restrict__ be_raw, const float* __restrict__ gam,
    const float* __restrict__ fc1w, const float* __restrict__ fc1b,
    const float* __restrict__ fc2w, const float* __restrict__ fc2b,
    const unsigned* __restrict__ UzT, const unsigned* __restrict__ UrT,
    const unsigned* __restrict__ UhT,
    float* __restrict__ out) {
    __shared__ __align__(16) unsigned char hS[2 * 640];   // bf16 h, 80B-padded 32-col slices
    __shared__ __align__(16) unsigned char rhS[2 * 640];  // bf16 r*h
    __shared__ float xs[2][TT];
    __shared__ float hid[2][HH];

    const int t    = threadIdx.x;
    const int s    = t & 7;                    // K-slice
    const int cp   = t >> 3;                   // col-pair 0..127
    const int col0 = 2 * cp;
    const bool p0 = (s & 1), p1 = (s & 2), p2 = (s & 4);
    const int b_own   = s & 1;                 // lanes s>=4 duplicate s-4
    const int col_own = col0 + ((s >> 1) & 1);
    const int b0 = blockIdx.x * 2;

    // ---- resident weights: Uz,Ur -> 2 cols x 4 uint4 each = 64 VGPRs ----
    uint4 wz[2][4], wr[2][4];
    {
        const uint4* pz = (const uint4*)(UzT + col0 * 128 + s * 16);
        const uint4* pr = (const uint4*)(UrT + col0 * 128 + s * 16);
#pragma unroll
        for (int u = 0; u < 4; ++u) {
            wz[0][u] = pz[u];      wz[1][u] = pz[32 + u];   // +128 dwords = next col
            wr[0][u] = pr[u];      wr[1][u] = pr[32 + u];
        }
    }
#pragma unroll
    for (int c = 0; c < 2; ++c)
#pragma unroll
        for (int u = 0; u < 4; ++u) { PIN4(wz[c][u]); PIN4(wr[c][u]); }

    // scalar params (uniform)
    const float omega = log1pf(__expf(om_raw[0])) + 1e-6f;
    const float aco   = sigmoidf_(al_raw[0]);
    const float bco   = sigmoidf_(be_raw[0]) * (1.0f - aco * 0.99f);
    const float gma   = gam[0];

    // per-lane (owned-column) params, exact fp32
    const float wz_o = Wzw[col_own], bz_o = Wzb[col_own] + Uzb[col_own];
    const float wr_o = Wrw[col_own], br_o = Wrb[col_own] + Urb[col_own];
    const float wh_o = Whw[col_own], bh_o = Whb[col_own] + Uhb[col_own];
    const float wg_o = Wgw[col_own], bg_o = Wgb[col_own];

    // stage x rows; zero h
    if (t < 512) xs[t >> 8][t & 255] = x[(b0 + (t >> 8)) * TT + (t & 255)];
    if (t < 320) ((unsigned*)hS)[t] = 0;

    float h_own = 0.f;
    float eps0 = 1e-6f, sig0 = 1e-6f, eps1 = 1e-6f, sig1 = 1e-6f;
    __syncthreads();

    const unsigned* uhb   = UhT + col0 * 128 + s * 16;
    const int       sl    = s * 80;
    const int       wroff = (col_own >> 5) * 40 + (col_own & 31);

    for (int tt = 0; tt < TT; ++tt) {
        const float x0 = xs[0][tt];
        const float x1 = xs[1][tt];
        const float g0 = omega + aco * eps0 + bco * sig0;
        const float g1 = omega + aco * eps1 + bco * sig1;
        eps0 = x0 * x0; sig0 = g0;
        eps1 = x1 * x1; sig1 = g1;
        const float x_o = p0 ? x1 : x0;
        const float g_o = p0 ? g1 : g0;

        // launder a zero so the Uh loads can't be hoisted out of the loop (streamed, not resident)
        unsigned lz = 0;
        asm volatile("" : "+v"(lz));
        const uint4* q0p = (const uint4*)(uhb + lz);         // col0 Uh slice
        const uint4* q1p = (const uint4*)(uhb + 128 + lz);   // col1
        uint4 u0[4], u1[4];
#pragma unroll
        for (int u = 0; u < 4; ++u) u0[u] = q0p[u];          // issue early; used in phase B

        // ---- phase A: z,r dots (weights from registers) ----
        float az[2][2], ar[2][2];
        az[0][0]=az[0][1]=az[1][0]=az[1][1]=0.f;
        ar[0][0]=ar[0][1]=ar[1][0]=ar[1][1]=0.f;
        {
            const uint4* hp = (const uint4*)(hS + sl);       // batch0 slice
            uint4 hq[4];
#pragma unroll
            for (int u = 0; u < 4; ++u) hq[u] = hp[u];
#pragma unroll
            for (int u = 0; u < 4; ++u) {
                DOT2Q(az[0][0], wz[0][u], hq[u]);
                DOT2Q(az[1][0], wz[1][u], hq[u]);
                DOT2Q(ar[0][0], wr[0][u], hq[u]);
                DOT2Q(ar[1][0], wr[1][u], hq[u]);
            }
        }
#pragma unroll
        for (int u = 0; u < 4; ++u) u1[u] = q1p[u];          // issue col1 Uh mid-phase
        {
            const uint4* hp = (const uint4*)(hS + 640 + sl); // batch1 slice
            uint4 hq[4];
#pragma unroll
            for (int u = 0; u < 4; ++u) hq[u] = hp[u];
#pragma unroll
            for (int u = 0; u < 4; ++u) {
                DOT2Q(az[0][1], wz[0][u], hq[u]);
                DOT2Q(az[1][1], wz[1][u], hq[u]);
                DOT2Q(ar[0][1], wr[0][u], hq[u]);
                DOT2Q(ar[1][1], wr[1][u], hq[u]);
            }
        }

        // ---- DPP reduce-scatter: xor1 picks batch, xor2 picks col, xor4 sums slice halves ----
        float zc0, zc1, rc0, rc1;
        RCOMB(zc0, az[0][0], az[0][1], p0, 0xB1);
        RCOMB(zc1, az[1][0], az[1][1], p0, 0xB1);
        RCOMB(rc0, ar[0][0], ar[0][1], p0, 0xB1);
        RCOMB(rc1, ar[1][0], ar[1][1], p0, 0xB1);
        float z2, r2;
        RCOMB(z2, zc0, zc1, p1, 0x4E);
        RCOMB(r2, rc0, rc1, p1, 0x4E);
        float accZ, accR;
        SUM4(accZ, z2, p2);
        SUM4(accR, r2, p2);

        const float z_own = sigmoidf_(accZ + x_o * wz_o + bz_o);
        const float r     = sigmoidf_(accR + x_o * wr_o + br_o);
        ((unsigned short*)(rhS + b_own * 640))[wroff] = (unsigned short)f2bf_rne(r * h_own);
        __syncthreads();

        // ---- phase B: candidate gate (Uh streamed in u0/u1) ----
        float ah[2][2];
        ah[0][0]=ah[0][1]=ah[1][0]=ah[1][1]=0.f;
        {
            const uint4* pp = (const uint4*)(rhS + sl);
            uint4 q[4];
#pragma unroll
            for (int u = 0; u < 4; ++u) q[u] = pp[u];
#pragma unroll
            for (int u = 0; u < 4; ++u) {
                DOT2Q(ah[0][0], u0[u], q[u]);
                DOT2Q(ah[1][0], u1[u], q[u]);
            }
        }
        {
            const uint4* pp = (const uint4*)(rhS + 640 + sl);
            uint4 q[4];
#pragma unroll
            for (int u = 0; u < 4; ++u) q[u] = pp[u];
#pragma unroll
            for (int u = 0; u < 4; ++u) {
                DOT2Q(ah[0][1], u0[u], q[u]);
                DOT2Q(ah[1][1], u1[u], q[u]);
            }
        }
        float hc0, hc1, h2;
        RCOMB(hc0, ah[0][0], ah[0][1], p0, 0xB1);
        RCOMB(hc1, ah[1][0], ah[1][1], p0, 0xB1);
        RCOMB(h2, hc0, hc1, p1, 0x4E);
        float accH;
        SUM4(accH, h2, p2);

        const float htld = tanhf_(accH + x_o * wh_o + bh_o);
        const float hh   = (1.f - z_own) * htld + z_own * h_own;
        const float hn   = tanhf_(hh + gma * (g_o * wg_o + bg_o));
        h_own = hn;
        ((unsigned short*)(hS + b_own * 640))[wroff] = (unsigned short)f2bf_rne(hn);
        __syncthreads();
    }

    // ---- stash exact fp32 h (xs no longer read) ----
    xs[b_own][col_own] = h_own;   // lanes s and s+4 write identical values
    __syncthreads();

    // ---- head: hid = relu(h @ fc1 + b1) ----
    if (t < 512) {
        const int b = t >> 8, j = t & 255;
        float acc = 0.f;
#pragma unroll 4
        for (int k = 0; k < HH; ++k) acc += xs[b][k] * fc1w[k * HH + j];
        hid[b][j] = fmaxf(acc + fc1b[j], 0.f);
    }
    __syncthreads();

    // ---- head: nn_scale / vol ----
    if (t < 2 * HOR) {
        const int b = t / HOR;
        const int c = t % HOR;
        float acc = fc2b[c];
        for (int k = 0; k < HH; ++k) acc += hid[b][k] * fc2w[k * HOR + c];
        const float sp = log1pf(__expf(acc));
        const float sg = b ? sig1 : sig0;
        const float vb = sqrtf(sg + 1e-8f);
        float vol = vb * (1.0f + sp);
        vol = fminf(fmaxf(vol, 0.01f), 10.0f);
        out[(b0 + b) * HOR + c] = vol;
    }
    if (t == 0) out[BATCH * HOR + b0]     = sig0;
    if (t == 1) out[BATCH * HOR + b0 + 1] = sig1;
}

extern "C" void kernel_launch(void* const* d_in, const int* in_sizes, int n_in,
                              void* d_out, int out_size, void* d_ws, size_t ws_size,
                              hipStream_t stream) {
    const float* x    = (const float*)d_in[0];
    const float* Wzw  = (const float*)d_in[1];
    const float* Wzb  = (const float*)d_in[2];
    const float* Uzw  = (const float*)d_in[3];
    const float* Uzb  = (const float*)d_in[4];
    const float* Wrw  = (const float*)d_in[5];
    const float* Wrb  = (const float*)d_in[6];
    const float* Urw  = (const float*)d_in[7];
    const float* Urb  = (const float*)d_in[8];
    const float* Whw  = (const float*)d_in[9];
    const float* Whb  = (const float*)d_in[10];
    const float* Uhw  = (const float*)d_in[11];
    const float* Uhb  = (const float*)d_in[12];
    const float* Wgw  = (const float*)d_in[13];
    const float* Wgb  = (const float*)d_in[14];
    const float* om   = (const float*)d_in[15];
    const float* al   = (const float*)d_in[16];
    const float* be   = (const float*)d_in[17];
    const float* ga   = (const float*)d_in[18];
    const float* fc1w = (const float*)d_in[19];
    const float* fc1b = (const float*)d_in[20];
    const float* fc2w = (const float*)d_in[21];
    const float* fc2b = (const float*)d_in[22];

    unsigned* UzT = (unsigned*)d_ws;       // 32768 uints each
    unsigned* UrT = UzT + 32768;
    unsigned* UhT = UrT + 32768;

    prep_kernel<<<384, 256, 0, stream>>>(Uzw, Urw, Uhw, UzT, UrT, UhT);
    gru_kernel<<<256, 1024, 0, stream>>>(x, Wzw, Wzb, Uzb, Wrw, Wrb, Urb, Whw, Whb, Uhb,
                                         Wgw, Wgb, om, al, be, ga, fc1w, fc1b, fc2w, fc2b,
                                         UzT, UrT, UhT, (float*)d_out);
}

// Round 8
// 786.875 us; speedup vs baseline: 1.5449x; 1.5449x over previous
//
#include <hip/hip_runtime.h>

#define BATCH 512
#define TT 256
#define HH 256
#define HOR 22

__device__ __forceinline__ float rcp_(float x) { return __builtin_amdgcn_rcpf(x); }
__device__ __forceinline__ float sigmoidf_(float x) { return rcp_(1.0f + __expf(-x)); }
__device__ __forceinline__ float tanhf_(float x) {
    float e = __expf(-2.0f * fabsf(x));
    float t = (1.0f - e) * rcp_(1.0f + e);
    return copysignf(t, x);
}
__device__ __forceinline__ unsigned f2bf_rne(float f) {
    unsigned u = __float_as_uint(f);
    unsigned lsb = (u >> 16) & 1u;
    return (u + 0x7FFFu + lsb) >> 16;
}

// v_dot2_f32_bf16: acc += a.lo*b.lo + a.hi*b.hi (packed bf16 pairs)
// NOTE (R7): VOP3P does NOT accept AGPR srcs on gfx950 -- VGPR only.
#define DOT2(acc, a, b) asm("v_dot2_f32_bf16 %0, %1, %2, %0" : "+v"(acc) : "v"(a), "v"(b))

// zero-instruction compiler barrier: pins a value into a VGPR, kills remat of
// its defining load. Works only when the register BUDGET allows residency;
// the budget is forced via the static-LDS occupancy limit (see dummy_lds).
#define PIN(v) asm volatile("" : "+v"(v))
#define PIN4(q) { PIN((q).x); PIN((q).y); PIN((q).z); PIN((q).w); }

// DPP cross-lane (VALU pipe, no LDS)
#define DPPF(x, ctrl) __int_as_float(__builtin_amdgcn_update_dpp(0, __float_as_int(x), (ctrl), 0xF, 0xF, true))
#define RCOMB(out, a, b, p, ctrl)                          \
    {                                                      \
        float _ta = (a) + DPPF((a), ctrl);                 \
        float _tb = (b) + DPPF((b), ctrl);                 \
        (out) = (p) ? _tb : _ta;                           \
    }
#define RCOMB4(out, a, b, p2v)                                         \
    {                                                                  \
        float _xa = (p2v) ? DPPF((a), 0x114) : DPPF((a), 0x104);       \
        float _xb = (p2v) ? DPPF((b), 0x114) : DPPF((b), 0x104);       \
        float _ta = (a) + _xa;                                         \
        float _tb = (b) + _xb;                                         \
        (out) = (p2v) ? _tb : _ta;                                     \
    }

// ---------------- prep: transpose U matrices to packed-bf16 rows UT[col][kpair] ----------------
__global__ __launch_bounds__(256) void prep_kernel(const float* __restrict__ Uz,
                                                   const float* __restrict__ Ur,
                                                   const float* __restrict__ Uh,
                                                   unsigned* __restrict__ UzT,
                                                   unsigned* __restrict__ UrT,
                                                   unsigned* __restrict__ UhT) {
    int tid = blockIdx.x * 256 + threadIdx.x;   // 0 .. 98303
    int m  = tid >> 15;
    int r  = tid & 32767;
    int j  = r & 255;
    int kp = r >> 8;
    const float* src = (m == 0) ? Uz : (m == 1) ? Ur : Uh;
    unsigned*    dst = (m == 0) ? UzT : (m == 1) ? UrT : UhT;
    float a0 = src[(2 * kp)     * HH + j];
    float a1 = src[(2 * kp + 1) * HH + j];
    dst[j * (HH / 2) + kp] = f2bf_rne(a0) | (f2bf_rne(a1) << 16);
}

// ---------------- persistent GRU: 1 WG = 2 batch rows, 512 thr = 64 col-quads x 8 K-slices ----
// dummy_lds pushes static LDS to ~84.5 KB -> only 1 WG/CU fits -> backend computes
// max occupancy = 2 waves/SIMD -> register budget 256/wave -> the 192 PINned
// weight dwords stay RESIDENT (R3-R6: budget 128/64 -> spill -> L2-BW wall at 33 TB/s).
__global__ __launch_bounds__(512) __attribute__((amdgpu_waves_per_eu(2, 2))) void gru_kernel(
    const float* __restrict__ x,
    const float* __restrict__ Wzw, const float* __restrict__ Wzb, const float* __restrict__ Uzb,
    const float* __restrict__ Wrw, const float* __restrict__ Wrb, const float* __restrict__ Urb,
    const float* __restrict__ Whw, const float* __restrict__ Whb, const float* __restrict__ Uhb,
    const float* __restrict__ Wgw, const float* __restrict__ Wgb,
    const float* __restrict__ om_raw, const float* __restrict__ al_raw,
    const float* __restrict__ be_raw, const float* __restrict__ gam,
    const float* __restrict__ fc1w, const float* __restrict__ fc1b,
    const float* __restrict__ fc2w, const float* __restrict__ fc2b,
    const unsigned* __restrict__ UzT, const unsigned* __restrict__ UrT,
    const unsigned* __restrict__ UhT,
    float* __restrict__ out) {
    // h / rh stored as bf16, 8 slices of 32 elems (64B data + 16B pad = 80B) per batch
    __shared__ __align__(16) unsigned char hS[2 * 640];
    __shared__ __align__(16) unsigned char rhS[2 * 640];
    __shared__ float xs[2][TT];
    __shared__ float hid[2][HH];
    __shared__ float dummy_lds[19456];   // 76 KB occupancy forcer (runtime-dead)

    const int t  = threadIdx.x;
    const int s  = t & 7;          // K-slice 0..7
    const int cq = t >> 3;         // column quad 0..63
    const bool p0 = (t & 1), p1 = (t & 2), p2 = (t & 4);
    const int c_own   = t & 3;             // owned column within quad
    const int b_own   = (t >> 2) & 1;      // owned batch
    const int col_own = 4 * cq + c_own;
    const int b0 = blockIdx.x * 2;

    // ---- per-thread weight registers: 3 gates x 4 cols x 4 uint4 = 192 VGPRs ----
    uint4 wz[4][4], wr[4][4], wh[4][4];
#pragma unroll
    for (int l = 0; l < 4; ++l) {
        const int base = (4 * cq + l) * 128 + s * 16;
        const uint4* pz = (const uint4*)(UzT + base);
        const uint4* pr = (const uint4*)(UrT + base);
        const uint4* ph = (const uint4*)(UhT + base);
#pragma unroll
        for (int u = 0; u < 4; ++u) { wz[l][u] = pz[u]; wr[l][u] = pr[u]; wh[l][u] = ph[u]; }
    }
#pragma unroll
    for (int l = 0; l < 4; ++l) {
#pragma unroll
        for (int u = 0; u < 4; ++u) { PIN4(wz[l][u]); PIN4(wr[l][u]); PIN4(wh[l][u]); }
    }

    // scalar params (uniform)
    const float om0   = om_raw[0];
    const float omega = log1pf(__expf(om0)) + 1e-6f;
    const float aco   = sigmoidf_(al_raw[0]);
    const float bco   = sigmoidf_(be_raw[0]) * (1.0f - aco * 0.99f);
    const float gma   = gam[0];

    // keep dummy_lds alive: runtime-false branch (om_raw ~ -8, never > 1e30)
    if (om0 > 1.0e30f) {
        dummy_lds[t] = om0;
        __syncthreads();
        out[t] = dummy_lds[(t * 37) & 511];
    }

    // per-lane (owned-column) params, exact fp32
    const float wz_o = Wzw[col_own], bz_o = Wzb[col_own] + Uzb[col_own];
    const float wr_o = Wrw[col_own], br_o = Wrb[col_own] + Urb[col_own];
    const float wh_o = Whw[col_own], bh_o = Whb[col_own] + Uhb[col_own];
    const float wg_o = Wgw[col_own], bg_o = Wgb[col_own];

    // stage x rows; zero h
    xs[t >> 8][t & 255] = x[(b0 + (t >> 8)) * TT + (t & 255)];
    if (t < 320) ((unsigned*)hS)[t] = 0;

    float h_own = 0.f, z_own = 0.f;
    float eps0 = 1e-6f, sig0 = 1e-6f, eps1 = 1e-6f, sig1 = 1e-6f;
    __syncthreads();

    const int sl_off = s * 80;
    const int wr_off = (col_own >> 5) * 40 + (col_own & 31);  // short index within batch plane

    for (int tt = 0; tt < TT; ++tt) {
        const float x0 = xs[0][tt];
        const float x1 = xs[1][tt];
        const float g0 = omega + aco * eps0 + bco * sig0;
        const float g1 = omega + aco * eps1 + bco * sig1;
        eps0 = x0 * x0; sig0 = g0;
        eps1 = x1 * x1; sig1 = g1;
        const float x_o = p2 ? x1 : x0;
        const float g_o = p2 ? g1 : g0;

        // ---- phase A: z,r partial dots over this thread's K-slice ----
        uint4 ha[4], hb[4];
        {
            const uint4* h0p = (const uint4*)(hS + sl_off);
            const uint4* h1p = (const uint4*)(hS + 640 + sl_off);
#pragma unroll
            for (int u = 0; u < 4; ++u) { ha[u] = h0p[u]; hb[u] = h1p[u]; }
        }
        float az[4][2], ar[4][2];
#pragma unroll
        for (int l = 0; l < 4; ++l) { az[l][0] = 0.f; az[l][1] = 0.f; ar[l][0] = 0.f; ar[l][1] = 0.f; }
#pragma unroll
        for (int l = 0; l < 4; ++l) {
#pragma unroll
            for (int u = 0; u < 4; ++u) {
                uint4 a = wz[l][u], b = wr[l][u];
                DOT2(az[l][0], a.x, ha[u].x); DOT2(az[l][0], a.y, ha[u].y);
                DOT2(az[l][0], a.z, ha[u].z); DOT2(az[l][0], a.w, ha[u].w);
                DOT2(az[l][1], a.x, hb[u].x); DOT2(az[l][1], a.y, hb[u].y);
                DOT2(az[l][1], a.z, hb[u].z); DOT2(az[l][1], a.w, hb[u].w);
                DOT2(ar[l][0], b.x, ha[u].x); DOT2(ar[l][0], b.y, ha[u].y);
                DOT2(ar[l][0], b.z, ha[u].z); DOT2(ar[l][0], b.w, ha[u].w);
                DOT2(ar[l][1], b.x, hb[u].x); DOT2(ar[l][1], b.y, hb[u].y);
                DOT2(ar[l][1], b.z, hb[u].z); DOT2(ar[l][1], b.w, hb[u].w);
            }
        }
        // ---- DPP reduce-scatter: lane ends with full sum for (c_own, b_own) ----
        float z1a[2][2], r1a[2][2];
        RCOMB(z1a[0][0], az[0][0], az[1][0], p0, 0xB1);
        RCOMB(z1a[0][1], az[0][1], az[1][1], p0, 0xB1);
        RCOMB(z1a[1][0], az[2][0], az[3][0], p0, 0xB1);
        RCOMB(z1a[1][1], az[2][1], az[3][1], p0, 0xB1);
        RCOMB(r1a[0][0], ar[0][0], ar[1][0], p0, 0xB1);
        RCOMB(r1a[0][1], ar[0][1], ar[1][1], p0, 0xB1);
        RCOMB(r1a[1][0], ar[2][0], ar[3][0], p0, 0xB1);
        RCOMB(r1a[1][1], ar[2][1], ar[3][1], p0, 0xB1);
        float z2a[2], r2a[2];
        RCOMB(z2a[0], z1a[0][0], z1a[1][0], p1, 0x4E);
        RCOMB(z2a[1], z1a[0][1], z1a[1][1], p1, 0x4E);
        RCOMB(r2a[0], r1a[0][0], r1a[1][0], p1, 0x4E);
        RCOMB(r2a[1], r1a[0][1], r1a[1][1], p1, 0x4E);
        float accZ, accR;
        RCOMB4(accZ, z2a[0], z2a[1], p2);
        RCOMB4(accR, r2a[0], r2a[1], p2);

        z_own = sigmoidf_(accZ + x_o * wz_o + bz_o);
        const float r = sigmoidf_(accR + x_o * wr_o + br_o);
        ((unsigned short*)(rhS + b_own * 640))[wr_off] = (unsigned short)f2bf_rne(r * h_own);
        __syncthreads();

        // ---- phase B: candidate gate ----
        uint4 pa[4], pb[4];
        {
            const uint4* r0p = (const uint4*)(rhS + sl_off);
            const uint4* r1p = (const uint4*)(rhS + 640 + sl_off);
#pragma unroll
            for (int u = 0; u < 4; ++u) { pa[u] = r0p[u]; pb[u] = r1p[u]; }
        }
        float ah[4][2];
#pragma unroll
        for (int l = 0; l < 4; ++l) { ah[l][0] = 0.f; ah[l][1] = 0.f; }
#pragma unroll
        for (int l = 0; l < 4; ++l) {
#pragma unroll
            for (int u = 0; u < 4; ++u) {
                uint4 a = wh[l][u];
                DOT2(ah[l][0], a.x, pa[u].x); DOT2(ah[l][0], a.y, pa[u].y);
                DOT2(ah[l][0], a.z, pa[u].z); DOT2(ah[l][0], a.w, pa[u].w);
                DOT2(ah[l][1], a.x, pb[u].x); DOT2(ah[l][1], a.y, pb[u].y);
                DOT2(ah[l][1], a.z, pb[u].z); DOT2(ah[l][1], a.w, pb[u].w);
            }
        }
        float h1a[2][2];
        RCOMB(h1a[0][0], ah[0][0], ah[1][0], p0, 0xB1);
        RCOMB(h1a[0][1], ah[0][1], ah[1][1], p0, 0xB1);
        RCOMB(h1a[1][0], ah[2][0], ah[3][0], p0, 0xB1);
        RCOMB(h1a[1][1], ah[2][1], ah[3][1], p0, 0xB1);
        float h2a[2];
        RCOMB(h2a[0], h1a[0][0], h1a[1][0], p1, 0x4E);
        RCOMB(h2a[1], h1a[0][1], h1a[1][1], p1, 0x4E);
        float accH;
        RCOMB4(accH, h2a[0], h2a[1], p2);

        const float htld = tanhf_(accH + x_o * wh_o + bh_o);
        const float hh   = (1.f - z_own) * htld + z_own * h_own;
        const float hn   = tanhf_(hh + gma * (g_o * wg_o + bg_o));
        h_own = hn;
        ((unsigned short*)(hS + b_own * 640))[wr_off] = (unsigned short)f2bf_rne(hn);
        __syncthreads();
    }

    // ---- stash exact fp32 h (reuse xs) ----
    xs[b_own][col_own] = h_own;
    __syncthreads();

    // ---- head: hid = relu(h @ fc1 + b1) ----
    {
        const int b = t >> 8, j = t & 255;
        float acc = 0.f;
#pragma unroll 4
        for (int k = 0; k < HH; ++k) acc += xs[b][k] * fc1w[k * HH + j];
        hid[b][j] = fmaxf(acc + fc1b[j], 0.f);
    }
    __syncthreads();

    // ---- head: nn_scale / vol ----
    if (t < 2 * HOR) {
        const int b = t / HOR;
        const int c = t % HOR;
        float acc = fc2b[c];
        for (int k = 0; k < HH; ++k) acc += hid[b][k] * fc2w[k * HOR + c];
        const float sp = log1pf(__expf(acc));
        const float sg = b ? sig1 : sig0;
        const float vb = sqrtf(sg + 1e-8f);
        float vol = vb * (1.0f + sp);
        vol = fminf(fmaxf(vol, 0.01f), 10.0f);
        out[(b0 + b) * HOR + c] = vol;
    }
    if (t == 0) out[BATCH * HOR + b0]     = sig0;
    if (t == 1) out[BATCH * HOR + b0 + 1] = sig1;
}

extern "C" void kernel_launch(void* const* d_in, const int* in_sizes, int n_in,
                              void* d_out, int out_size, void* d_ws, size_t ws_size,
                              hipStream_t stream) {
    const float* x    = (const float*)d_in[0];
    const float* Wzw  = (const float*)d_in[1];
    const float* Wzb  = (const float*)d_in[2];
    const float* Uzw  = (const float*)d_in[3];
    const float* Uzb  = (const float*)d_in[4];
    const float* Wrw  = (const float*)d_in[5];
    const float* Wrb  = (const float*)d_in[6];
    const float* Urw  = (const float*)d_in[7];
    const float* Urb  = (const float*)d_in[8];
    const float* Whw  = (const float*)d_in[9];
    const float* Whb  = (const float*)d_in[10];
    const float* Uhw  = (const float*)d_in[11];
    const float* Uhb  = (const float*)d_in[12];
    const float* Wgw  = (const float*)d_in[13];
    const float* Wgb  = (const float*)d_in[14];
    const float* om   = (const float*)d_in[15];
    const float* al   = (const float*)d_in[16];
    const float* be   = (const float*)d_in[17];
    const float* ga   = (const float*)d_in[18];
    const float* fc1w = (const float*)d_in[19];
    const float* fc1b = (const float*)d_in[20];
    const float* fc2w = (const float*)d_in[21];
    const float* fc2b = (const float*)d_in[22];

    unsigned* UzT = (unsigned*)d_ws;       // 32768 uints each
    unsigned* UrT = UzT + 32768;
    unsigned* UhT = UrT + 32768;

    prep_kernel<<<384, 256, 0, stream>>>(Uzw, Urw, Uhw, UzT, UrT, UhT);
    gru_kernel<<<256, 512, 0, stream>>>(x, Wzw, Wzb, Uzb, Wrw, Wrb, Urb, Whw, Whb, Uhb,
                                        Wgw, Wgb, om, al, be, ga, fc1w, fc1b, fc2w, fc2b,
                                        UzT, UrT, UhT, (float*)d_out);
}